// Round 1
// baseline (6757.388 us; speedup 1.0000x reference)
//
#include <hip/hip_runtime.h>

typedef _Float16 half8 __attribute__((ext_vector_type(8)));
typedef float floatx4 __attribute__((ext_vector_type(4)));
typedef unsigned long long u64;
typedef unsigned int u32;
typedef unsigned short u16;

#define T_LEN 16384
#define DM 512
#define NC 2048      // 4*DM
#define NG 16        // groups
#define NR 16        // segment rows (batch) per group
#define WPG 16       // workgroups per group

struct Meta { int S; int use_h0; int steps_g[NG]; };

union FragU { u64 q[2]; half8 v; };

__device__ __forceinline__ float sigf(float x) { return 1.0f / (1.0f + __expf(-x)); }
__device__ __forceinline__ float tanh_f(float x) { return 1.0f - 2.0f / (__expf(2.0f * x) + 1.0f); }

// ---------------- zero workspace region ----------------
__global__ void zero_kernel(u32* __restrict__ p, size_t nwords) {
    size_t i = (size_t)blockIdx.x * blockDim.x + threadIdx.x;
    size_t stride = (size_t)gridDim.x * blockDim.x;
    for (; i < nwords; i += stride) p[i] = 0u;
}

// ---------------- f32 -> f16 pack (row-major) ----------------
__global__ void pack_f16_kernel(const float* __restrict__ src, _Float16* __restrict__ dst, int n8) {
    int i = blockIdx.x * blockDim.x + threadIdx.x;
    if (i >= n8) return;
    const floatx4* s = (const floatx4*)src + (size_t)i * 2;
    floatx4 a = s[0], b = s[1];
    half8 o;
    o[0] = (_Float16)a[0]; o[1] = (_Float16)a[1]; o[2] = (_Float16)a[2]; o[3] = (_Float16)a[3];
    o[4] = (_Float16)b[0]; o[5] = (_Float16)b[1]; o[6] = (_Float16)b[2]; o[7] = (_Float16)b[3];
    ((half8*)dst)[i] = o;
}

// ---------------- weight pack to MFMA B-fragment order ----------------
// Logical col for tile tt (= cch*4+q): q*512 + cch*16 + n.  k = kt*32 + h*8 + j.
__global__ __launch_bounds__(256) void pack_w_kernel(const float* __restrict__ src, half8* __restrict__ dst) {
    int wid = blockIdx.x * 4 + (threadIdx.x >> 6);  // 2048 = 128 tiles * 16 kt
    int l = threadIdx.x & 63;
    int tt = wid >> 4, kt = wid & 15;
    int q = tt & 3, cch = tt >> 2;
    int col = q * 512 + cch * 16 + (l & 15);
    int h = l >> 4;
    half8 o;
#pragma unroll
    for (int jj = 0; jj < 8; jj++) o[jj] = (_Float16)src[(size_t)(kt * 32 + h * 8 + jj) * NC + col];
    dst[(tt * 16 + kt) * 64 + l] = o;
}

// ---------------- prep: term dtype detect, segment extraction, chains ----------------
__global__ void prep_kernel(const void* __restrict__ termraw, const float* __restrict__ h0,
                            int* __restrict__ seg_start, int* __restrict__ seg_len,
                            Meta* __restrict__ meta, _Float16* __restrict__ Hbuf) {
    __shared__ int cnts[256], offs[256];
    __shared__ int nzm, oddnz, totS;
    __shared__ int chain[256];
    int tid = threadIdx.x;
    if (tid == 0) { nzm = 0; oddnz = 0; }
    __syncthreads();
    const unsigned char* tb = (const unsigned char*)termraw;
    const int* ti = (const int*)termraw;
    // byte-pattern scan over first T_LEN bytes (safe for every candidate dtype)
    int lm = 0;
    for (int i = tid; i < T_LEN; i += 256) {
        if (tb[i]) {
            int p = i & 3;
            if (p == 1 || p == 2) lm |= 1;
            else if (p == 3) lm |= 2;
            else lm |= 4;
        }
    }
    if (lm) atomicOr(&nzm, lm);
    __syncthreads();
    int mm = nzm;
    int bytemode = (mm & 1) ? 1 : 0;
    int floatmode = (!bytemode && (mm & 2)) ? 1 : 0;
    // int64 vs int32: odd 32-bit words all zero => int64 (safe to read 64KB: only reached for int dtypes)
    int lo = 0;
    if (!bytemode && !floatmode) {
        for (int k2 = 2 * tid + 1; k2 < T_LEN; k2 += 512) if (ti[k2]) lo = 1;
    }
    if (lo) atomicOr(&oddnz, 1);
    __syncthreads();
    int i64mode = (!bytemode && !floatmode && oddnz == 0 && (mm & 4)) ? 1 : 0;
    const float* tf = (const float*)termraw;

    auto termAt = [&](int t) -> int {
        if (bytemode) return tb[t] != 0;
        if (floatmode) return tf[t] != 0.0f;
        if (i64mode) return (ti[2 * t] != 0) || (ti[2 * t + 1] != 0);
        return ti[t] != 0;
    };

    // segment starts: t==0 or term[t]
    int base = tid * 64;
    int cnt = 0;
    for (int k = 0; k < 64; k++) {
        int t = base + k;
        if (t == 0 || termAt(t)) cnt++;
    }
    cnts[tid] = cnt;
    __syncthreads();
    if (tid == 0) {
        int a = 0;
        for (int i = 0; i < 256; i++) { offs[i] = a; a += cnts[i]; }
        totS = a;
        meta->S = a;
    }
    __syncthreads();
    int S = totS;
    {
        int o = offs[tid];
        for (int k = 0; k < 64; k++) {
            int t = base + k;
            if (t == 0 || termAt(t)) seg_start[o++] = t;
        }
    }
    __syncthreads();
    for (int i = tid; i < S; i += 256)
        seg_len[i] = ((i + 1 < S) ? seg_start[i + 1] : T_LEN) - seg_start[i];
    __syncthreads();
    // slot chains: seg i -> group i%16, row (i/16)%16, chain pos i/256
    {
        int g = tid >> 4, r = tid & 15;
        int tot = 0;
        for (int i = g + 16 * r; i < S; i += 256) tot += seg_len[i];
        chain[tid] = tot;
    }
    __syncthreads();
    if (tid < NG) {
        int mx = 0;
        for (int r = 0; r < 16; r++) mx = max(mx, chain[tid * 16 + r]);
        meta->steps_g[tid] = mx;
    }
    int u = termAt(0);
    if (tid == 0) meta->use_h0 = !u;
    if (!u) {  // group0,parity0,row0 <- h0
        for (int d2 = tid; d2 < DM; d2 += 256) Hbuf[d2] = (_Float16)h0[d2];
    }
}

// ---------------- XW = inputs @ Wx + b (fp16 MFMA, packed-col order) ----------------
template <bool XWH>
__global__ __launch_bounds__(256) void xw_gemm_kernel(const half8* __restrict__ A, const half8* __restrict__ B,
                                                      const float* __restrict__ bias, void* __restrict__ XW) {
    int bx = blockIdx.x, by = blockIdx.y;
    int w = threadIdx.x >> 6, l = threadIdx.x & 63;
    int mbase = bx * 64 + w * 16;
    int h = l >> 4, n = l & 15;
    floatx4 acc[8] = {};
    int arow = mbase + n;
#pragma unroll
    for (int kt = 0; kt < 16; kt++) {
        half8 a = A[(size_t)arow * 64 + kt * 4 + h];
#pragma unroll
        for (int nt = 0; nt < 8; nt++)
            acc[nt] = __builtin_amdgcn_mfma_f32_16x16x32_f16(a, B[((by * 8 + nt) * 16 + kt) * 64 + l], acc[nt], 0, 0, 0);
    }
#pragma unroll
    for (int nt = 0; nt < 8; nt++) {
        int tt = by * 8 + nt, q = tt & 3, cch = tt >> 2;
        float bv = bias[q * 512 + cch * 16 + n];
#pragma unroll
        for (int r = 0; r < 4; r++) {
            int row = mbase + h * 4 + r;
            float v = acc[nt][r] + bv;
            size_t idx = (size_t)row * NC + tt * 16 + n;
            if (XWH) ((_Float16*)XW)[idx] = (_Float16)v;
            else ((float*)XW)[idx] = v;
        }
    }
}

// ---------------- recurrent scan: 16 groups x 16 WGs, Wh resident in VGPRs ----------------
template <bool XWH>
__global__ __launch_bounds__(128, 1) void scan_kernel(
    const half8* __restrict__ PW, const void* __restrict__ XW,
    const float* __restrict__ c0,
    const int* __restrict__ seg_start, const int* __restrict__ seg_len,
    const Meta* __restrict__ meta,
    u64* __restrict__ Hbuf, int* __restrict__ arrive,
    float* __restrict__ out) {
    const int b = blockIdx.x;
    const int g = (b & 7) * 2 + (b >> 7);   // XCD-local groups (perf hint only)
    const int jj = (b >> 3) & 15;
    const int tid = threadIdx.x;
    const int w = tid >> 6, l = tid & 63;
    const int c = jj * 2 + w;               // dim chunk 0..31 (16 dims each)
    const int S = meta->S;
    const int steps = meta->steps_g[g];
    if (steps <= 0) return;
    const int use_h0 = meta->use_h0;
    const int n = l & 15, h = l >> 4;
    const int d = c * 16 + n;

    __shared__ int rs_active[NR], rs_zero[NR], rs_t[NR];
    __shared__ int rs_seg[NR], rs_end[NR], rs_t0[NR], rs_s0[NR];
    __shared__ __align__(16) u16 hstage[2][NR][16];

    // resident Wh B-fragments: 4 gate tiles x 16 k-steps (256 VGPRs)
    half8 bf[4][16];
#pragma unroll
    for (int q = 0; q < 4; q++)
#pragma unroll
        for (int kt = 0; kt < 16; kt++)
            bf[q][kt] = PW[((c * 4 + q) * 16 + kt) * 64 + l];

    float cc[4];
#pragma unroll
    for (int r = 0; r < 4; r++) {
        int row = h * 4 + r;
        cc[r] = (g == 0 && row == 0 && use_h0) ? c0[d] : 0.0f;
    }

    FragU zu; zu.q[0] = 0; zu.q[1] = 0;
    const half8 zfrag = zu.v;

    int* arr = arrive + (size_t)g * T_LEN;
    float* outH = out;
    float* outC = out + (size_t)T_LEN * DM;
    float* outH2 = out + 2 * (size_t)T_LEN * DM;

    for (int s = 0; s < steps; ++s) {
        if (tid < NR) {
            int r = tid;
            if (s == 0) {
                int seg = g + 16 * r;
                if (seg < S) {
                    rs_active[r] = 1; rs_zero[r] = 0; rs_seg[r] = seg;
                    rs_t0[r] = seg_start[seg]; rs_s0[r] = 0; rs_end[r] = seg_len[seg];
                    rs_t[r] = seg_start[seg];
                } else {
                    rs_active[r] = 0; rs_zero[r] = 1; rs_end[r] = 0x7fffffff; rs_t[r] = 0;
                }
            } else {
                int z = !rs_active[r];
                if (rs_active[r] && s == rs_end[r]) {
                    int seg = rs_seg[r] + 256;
                    if (seg < S) {
                        rs_seg[r] = seg; rs_t0[r] = seg_start[seg]; rs_s0[r] = s;
                        rs_end[r] = s + seg_len[seg];
                        z = 1;
                    } else { rs_active[r] = 0; z = 1; }
                }
                rs_zero[r] = z;
                rs_t[r] = rs_active[r] ? (rs_t0[r] + (s - rs_s0[r])) : 0;
            }
        }
        __syncthreads();

        // x-side preactivation gather (issued early, independent of H)
        int tr[4]; int act[4];
#pragma unroll
        for (int r = 0; r < 4; r++) { int row = h * 4 + r; tr[r] = rs_t[row]; act[r] = rs_active[row]; }
        float xwv[4][4];
#pragma unroll
        for (int q = 0; q < 4; q++)
#pragma unroll
            for (int r = 0; r < 4; r++) {
                size_t idx = (size_t)tr[r] * NC + (c * 4 + q) * 16 + n;
                xwv[q][r] = XWH ? (float)((const _Float16*)XW)[idx] : ((const float*)XW)[idx];
            }

        const int rp = s & 1;
        u64* Hr = Hbuf + (size_t)(g * 2 + rp) * (NR * DM / 4);
        u64* Hw = Hbuf + (size_t)(g * 2 + (rp ^ 1)) * (NR * DM / 4);

        // A fragments: H rows (agent-scope atomic loads = cross-CU coherent)
        const int m = n;
        const int mz = rs_zero[m];
        half8 afr[16];
#pragma unroll
        for (int kt = 0; kt < 16; kt++) {
            FragU u;
            u.q[0] = __hip_atomic_load(&Hr[m * 128 + kt * 8 + h * 2], __ATOMIC_RELAXED, __HIP_MEMORY_SCOPE_AGENT);
            u.q[1] = __hip_atomic_load(&Hr[m * 128 + kt * 8 + h * 2 + 1], __ATOMIC_RELAXED, __HIP_MEMORY_SCOPE_AGENT);
            afr[kt] = mz ? zfrag : u.v;
        }

        floatx4 acc[4] = {};
#pragma unroll
        for (int kt = 0; kt < 16; kt++) {
#pragma unroll
            for (int q = 0; q < 4; q++)
                acc[q] = __builtin_amdgcn_mfma_f32_16x16x32_f16(afr[kt], bf[q][kt], acc[q], 0, 0, 0);
        }

        // gates + state update + outputs
#pragma unroll
        for (int r = 0; r < 4; r++) {
            int row = h * 4 + r;
            float zi = acc[0][r] + xwv[0][r];
            float zf = acc[1][r] + xwv[1][r];
            float zg = acc[2][r] + xwv[2][r];
            float zo = acc[3][r] + xwv[3][r];
            float cprev = rs_zero[row] ? 0.0f : cc[r];
            float cn = sigf(zf) * cprev + sigf(zi) * tanh_f(zg);
            float hn = sigf(zo) * tanh_f(cn);
            cc[r] = cn;
            hstage[w][row][n] = __builtin_bit_cast(u16, (_Float16)hn);
            if (act[r]) {
                size_t oo = (size_t)tr[r] * DM + d;
                outH[oo] = hn; outC[oo] = cn; outH2[oo] = hn;
            }
        }

        // pack wave-locally via LDS, publish 8B atomic stores
        u64 pk = ((const u64*)&hstage[w][0][0])[l];
        __hip_atomic_store(&Hw[(size_t)(l >> 2) * 128 + c * 4 + (l & 3)], pk, __ATOMIC_RELAXED, __HIP_MEMORY_SCOPE_AGENT);

        __syncthreads();  // drains this WG's vmem before flagging
        if (tid == 0) __hip_atomic_fetch_add(&arr[s], 1, __ATOMIC_RELEASE, __HIP_MEMORY_SCOPE_AGENT);
        while (__hip_atomic_load(&arr[s], __ATOMIC_ACQUIRE, __HIP_MEMORY_SCOPE_AGENT) < WPG)
            __builtin_amdgcn_s_sleep(2);
    }
}

extern "C" void kernel_launch(void* const* d_in, const int* in_sizes, int n_in,
                              void* d_out, int out_size, void* d_ws, size_t ws_size,
                              hipStream_t stream) {
    const float* inputs = (const float*)d_in[0];
    const void* terms = d_in[1];
    const float* c0 = (const float*)d_in[2];
    const float* h0 = (const float*)d_in[3];
    const float* Wx = (const float*)d_in[4];
    const float* Wh = (const float*)d_in[5];
    const float* bias = (const float*)d_in[6];
    float* out = (float*)d_out;

    size_t szXWf = (size_t)T_LEN * NC * 4;
    size_t szXWh = (size_t)T_LEN * NC * 2;
    size_t rest = ((size_t)T_LEN * DM * 2 + 256) + 2 * ((size_t)DM * NC * 2 + 256)
                + 2 * ((size_t)(T_LEN + 2) * 4 + 256)
                + (2ull * NG * NR * DM * 2 + 256) + ((size_t)NG * T_LEN * 4 + 256) + 512;
    bool xwh = (ws_size < rest + szXWf + 256);

    size_t off = 0;
    auto take = [&](size_t bts) { size_t cur = off; off = (off + bts + 255) & ~(size_t)255; return cur; };
    size_t offXW = take(xwh ? szXWh : szXWf);
    size_t offAin = take((size_t)T_LEN * DM * 2);
    size_t offPX = take((size_t)DM * NC * 2);
    size_t offPW = take((size_t)DM * NC * 2);
    size_t offSS = take((size_t)(T_LEN + 2) * 4);
    size_t offSL = take((size_t)(T_LEN + 2) * 4);
    size_t offH = take(2ull * NG * NR * DM * 2);
    size_t offAR = take((size_t)NG * T_LEN * 4);
    size_t offME = take(256);
    size_t total = off;
    (void)offME;

    char* W = (char*)d_ws;
    _Float16* Ain = (_Float16*)(W + offAin);
    half8* PX = (half8*)(W + offPX);
    half8* PWp = (half8*)(W + offPW);
    int* segS = (int*)(W + offSS);
    int* segL = (int*)(W + offSL);
    Meta* meta = (Meta*)(W + offME);
    void* XWp = (void*)(W + offXW);

    size_t zwords = (total - offH) / 4;  // Hbuf + arrive + meta contiguous
    zero_kernel<<<256, 256, 0, stream>>>((u32*)(W + offH), zwords);
    pack_f16_kernel<<<(T_LEN * DM / 8 + 255) / 256, 256, 0, stream>>>(inputs, Ain, T_LEN * DM / 8);
    pack_w_kernel<<<512, 256, 0, stream>>>(Wx, PX);
    pack_w_kernel<<<512, 256, 0, stream>>>(Wh, PWp);
    prep_kernel<<<1, 256, 0, stream>>>(terms, h0, segS, segL, meta, (_Float16*)(W + offH));

    dim3 gg(T_LEN / 64, NC / 128);
    if (xwh) {
        xw_gemm_kernel<true><<<gg, 256, 0, stream>>>((const half8*)Ain, (const half8*)PX, bias, XWp);
        scan_kernel<true><<<256, 128, 0, stream>>>((const half8*)PWp, XWp, c0, segS, segL, meta,
                                                   (u64*)(W + offH), (int*)(W + offAR), out);
    } else {
        xw_gemm_kernel<false><<<gg, 256, 0, stream>>>((const half8*)Ain, (const half8*)PX, bias, XWp);
        scan_kernel<false><<<256, 128, 0, stream>>>((const half8*)PWp, XWp, c0, segS, segL, meta,
                                                    (u64*)(W + offH), (int*)(W + offAR), out);
    }
}

// Round 2
// 5666.174 us; speedup vs baseline: 1.1926x; 1.1926x over previous
//
#include <hip/hip_runtime.h>

typedef _Float16 half8 __attribute__((ext_vector_type(8)));
typedef float floatx4 __attribute__((ext_vector_type(4)));
typedef unsigned long long u64;
typedef unsigned int u32;
typedef unsigned short u16;

#define T_LEN 16384
#define DM 512
#define NC 2048      // 4*DM
#define NG 16        // groups
#define NR 16        // segment rows (batch) per group
#define WPG 16       // workgroups per group

struct Meta { int S; int use_h0; int steps_g[NG]; };

union FragU { u64 q[2]; half8 v; };

__device__ __forceinline__ float sigf(float x) { return 1.0f / (1.0f + __expf(-x)); }
__device__ __forceinline__ float tanh_f(float x) { return 1.0f - 2.0f / (__expf(2.0f * x) + 1.0f); }

// ---------------- zero workspace region ----------------
__global__ void zero_kernel(u32* __restrict__ p, size_t nwords) {
    size_t i = (size_t)blockIdx.x * blockDim.x + threadIdx.x;
    size_t stride = (size_t)gridDim.x * blockDim.x;
    for (; i < nwords; i += stride) p[i] = 0u;
}

// ---------------- f32 -> f16 pack (row-major) ----------------
__global__ void pack_f16_kernel(const float* __restrict__ src, _Float16* __restrict__ dst, int n8) {
    int i = blockIdx.x * blockDim.x + threadIdx.x;
    if (i >= n8) return;
    const floatx4* s = (const floatx4*)src + (size_t)i * 2;
    floatx4 a = s[0], b = s[1];
    half8 o;
    o[0] = (_Float16)a[0]; o[1] = (_Float16)a[1]; o[2] = (_Float16)a[2]; o[3] = (_Float16)a[3];
    o[4] = (_Float16)b[0]; o[5] = (_Float16)b[1]; o[6] = (_Float16)b[2]; o[7] = (_Float16)b[3];
    ((half8*)dst)[i] = o;
}

// ---------------- weight pack to MFMA B-fragment order ----------------
// Logical col for tile tt (= cch*4+q): q*512 + cch*16 + n.  k = kt*32 + h*8 + j.
__global__ __launch_bounds__(256) void pack_w_kernel(const float* __restrict__ src, half8* __restrict__ dst) {
    int wid = blockIdx.x * 4 + (threadIdx.x >> 6);  // 2048 = 128 tiles * 16 kt
    int l = threadIdx.x & 63;
    int tt = wid >> 4, kt = wid & 15;
    int q = tt & 3, cch = tt >> 2;
    int col = q * 512 + cch * 16 + (l & 15);
    int h = l >> 4;
    half8 o;
#pragma unroll
    for (int jj = 0; jj < 8; jj++) o[jj] = (_Float16)src[(size_t)(kt * 32 + h * 8 + jj) * NC + col];
    dst[(tt * 16 + kt) * 64 + l] = o;
}

// ---------------- prep: term dtype detect, segment extraction, chains ----------------
__global__ void prep_kernel(const void* __restrict__ termraw, const float* __restrict__ h0,
                            int* __restrict__ seg_start, int* __restrict__ seg_len,
                            Meta* __restrict__ meta, _Float16* __restrict__ Hbuf) {
    __shared__ int cnts[256], offs[256];
    __shared__ int nzm, oddnz, totS;
    __shared__ int chain[256];
    int tid = threadIdx.x;
    if (tid == 0) { nzm = 0; oddnz = 0; }
    __syncthreads();
    const unsigned char* tb = (const unsigned char*)termraw;
    const int* ti = (const int*)termraw;
    int lm = 0;
    for (int i = tid; i < T_LEN; i += 256) {
        if (tb[i]) {
            int p = i & 3;
            if (p == 1 || p == 2) lm |= 1;
            else if (p == 3) lm |= 2;
            else lm |= 4;
        }
    }
    if (lm) atomicOr(&nzm, lm);
    __syncthreads();
    int mm = nzm;
    int bytemode = (mm & 1) ? 1 : 0;
    int floatmode = (!bytemode && (mm & 2)) ? 1 : 0;
    int lo = 0;
    if (!bytemode && !floatmode) {
        for (int k2 = 2 * tid + 1; k2 < T_LEN; k2 += 512) if (ti[k2]) lo = 1;
    }
    if (lo) atomicOr(&oddnz, 1);
    __syncthreads();
    int i64mode = (!bytemode && !floatmode && oddnz == 0 && (mm & 4)) ? 1 : 0;
    const float* tf = (const float*)termraw;

    auto termAt = [&](int t) -> int {
        if (bytemode) return tb[t] != 0;
        if (floatmode) return tf[t] != 0.0f;
        if (i64mode) return (ti[2 * t] != 0) || (ti[2 * t + 1] != 0);
        return ti[t] != 0;
    };

    int base = tid * 64;
    int cnt = 0;
    for (int k = 0; k < 64; k++) {
        int t = base + k;
        if (t == 0 || termAt(t)) cnt++;
    }
    cnts[tid] = cnt;
    __syncthreads();
    if (tid == 0) {
        int a = 0;
        for (int i = 0; i < 256; i++) { offs[i] = a; a += cnts[i]; }
        totS = a;
        meta->S = a;
    }
    __syncthreads();
    int S = totS;
    {
        int o = offs[tid];
        for (int k = 0; k < 64; k++) {
            int t = base + k;
            if (t == 0 || termAt(t)) seg_start[o++] = t;
        }
    }
    __syncthreads();
    for (int i = tid; i < S; i += 256)
        seg_len[i] = ((i + 1 < S) ? seg_start[i + 1] : T_LEN) - seg_start[i];
    __syncthreads();
    {
        int g = tid >> 4, r = tid & 15;
        int tot = 0;
        for (int i = g + 16 * r; i < S; i += 256) tot += seg_len[i];
        chain[tid] = tot;
    }
    __syncthreads();
    if (tid < NG) {
        int mx = 0;
        for (int r = 0; r < 16; r++) mx = max(mx, chain[tid * 16 + r]);
        meta->steps_g[tid] = mx;
    }
    int u = termAt(0);
    if (tid == 0) meta->use_h0 = !u;
    if (!u) {
        for (int d2 = tid; d2 < DM; d2 += 256) Hbuf[d2] = (_Float16)h0[d2];
    }
}

// ---------------- XW = inputs @ Wx + b (fp16 MFMA, packed-col order) ----------------
template <bool XWH>
__global__ __launch_bounds__(256) void xw_gemm_kernel(const half8* __restrict__ A, const half8* __restrict__ B,
                                                      const float* __restrict__ bias, void* __restrict__ XW) {
    int bx = blockIdx.x, by = blockIdx.y;
    int w = threadIdx.x >> 6, l = threadIdx.x & 63;
    int mbase = bx * 64 + w * 16;
    int h = l >> 4, n = l & 15;
    floatx4 acc[8] = {};
    int arow = mbase + n;
#pragma unroll
    for (int kt = 0; kt < 16; kt++) {
        half8 a = A[(size_t)arow * 64 + kt * 4 + h];
#pragma unroll
        for (int nt = 0; nt < 8; nt++)
            acc[nt] = __builtin_amdgcn_mfma_f32_16x16x32_f16(a, B[((by * 8 + nt) * 16 + kt) * 64 + l], acc[nt], 0, 0, 0);
    }
#pragma unroll
    for (int nt = 0; nt < 8; nt++) {
        int tt = by * 8 + nt, q = tt & 3, cch = tt >> 2;
        float bv = bias[q * 512 + cch * 16 + n];
#pragma unroll
        for (int r = 0; r < 4; r++) {
            int row = mbase + h * 4 + r;
            float v = acc[nt][r] + bv;
            size_t idx = (size_t)row * NC + tt * 16 + n;
            if (XWH) ((_Float16*)XW)[idx] = (_Float16)v;
            else ((float*)XW)[idx] = v;
        }
    }
}

// ---------------- recurrent scan: 16 groups x 16 WGs, Wh resident in VGPRs ----------------
// Sync protocol v2: per-writer release flags, relaxed polling + one acquire fence,
// rs-update + XW loads overlapped with the spin, out-stores after flag publish.
template <bool XWH>
__global__ __launch_bounds__(128, 1) void scan_kernel(
    const half8* __restrict__ PW, const void* __restrict__ XW,
    const float* __restrict__ c0,
    const int* __restrict__ seg_start, const int* __restrict__ seg_len,
    const Meta* __restrict__ meta,
    u64* __restrict__ Hbuf, int* __restrict__ flags,
    float* __restrict__ out) {
    const int b = blockIdx.x;
    const int g = (b & 7) * 2 + (b >> 7);   // XCD-local groups (perf hint only)
    const int jj = (b >> 3) & 15;
    const int tid = threadIdx.x;
    const int w = tid >> 6, l = tid & 63;
    const int c = jj * 2 + w;               // dim chunk 0..31 (16 dims each)
    const int S = meta->S;
    const int steps = meta->steps_g[g];
    if (steps <= 0) return;
    const int use_h0 = meta->use_h0;
    const int n = l & 15, h = l >> 4;
    const int d = c * 16 + n;

    __shared__ int rs_active[NR], rs_zero[NR], rs_t[NR];
    __shared__ int rs_seg[NR], rs_end[NR], rs_t0[NR], rs_s0[NR];
    __shared__ __align__(16) u16 hstage[2][NR][16];

    // resident Wh B-fragments: 4 gate tiles x 16 k-steps (256 VGPRs)
    half8 bf[4][16];
#pragma unroll
    for (int q = 0; q < 4; q++)
#pragma unroll
        for (int kt = 0; kt < 16; kt++)
            bf[q][kt] = PW[((c * 4 + q) * 16 + kt) * 64 + l];

    float cc[4];
#pragma unroll
    for (int r = 0; r < 4; r++) {
        int row = h * 4 + r;
        cc[r] = (g == 0 && row == 0 && use_h0) ? c0[d] : 0.0f;
    }

    FragU zu; zu.q[0] = 0; zu.q[1] = 0;
    const half8 zfrag = zu.v;

    int* fl = flags + g * WPG;
    const int me = l & 15;      // flag index this lane polls
    const int myflag = b >> 3;  // wait—must be unique writer id within group; see below
    // writer id within group: blocks of group g are b = (g>>1) + 8*jj + 128*(g&1), jj=0..15 -> use jj
    const int wid_in_g = jj;

    float* outH = out;
    float* outC = out + (size_t)T_LEN * DM;
    float* outH2 = out + 2 * (size_t)T_LEN * DM;
    (void)myflag;

    for (int s = 0; s < steps; ++s) {
        // ---- rs state for step s (independent of peers' H) ----
        if (tid < NR) {
            int r = tid;
            if (s == 0) {
                int seg = g + 16 * r;
                if (seg < S) {
                    rs_active[r] = 1; rs_zero[r] = 0; rs_seg[r] = seg;
                    rs_t0[r] = seg_start[seg]; rs_s0[r] = 0; rs_end[r] = seg_len[seg];
                    rs_t[r] = seg_start[seg];
                } else {
                    rs_active[r] = 0; rs_zero[r] = 1; rs_end[r] = 0x7fffffff; rs_t[r] = 0;
                }
            } else {
                int z = !rs_active[r];
                if (rs_active[r] && s == rs_end[r]) {
                    int seg = rs_seg[r] + 256;
                    if (seg < S) {
                        rs_seg[r] = seg; rs_t0[r] = seg_start[seg]; rs_s0[r] = s;
                        rs_end[r] = s + seg_len[seg];
                        z = 1;
                    } else { rs_active[r] = 0; z = 1; }
                }
                rs_zero[r] = z;
                rs_t[r] = rs_active[r] ? (rs_t0[r] + (s - rs_s0[r])) : 0;
            }
        }
        __syncthreads();

        // ---- issue XW gather for step s (overlaps with the spin below) ----
        int tr[4]; int act[4];
#pragma unroll
        for (int r = 0; r < 4; r++) { int row = h * 4 + r; tr[r] = rs_t[row]; act[r] = rs_active[row]; }
        float xwv[4][4];
#pragma unroll
        for (int q = 0; q < 4; q++)
#pragma unroll
            for (int r = 0; r < 4; r++) {
                size_t idx = (size_t)tr[r] * NC + (c * 4 + q) * 16 + n;
                xwv[q][r] = XWH ? (float)((const _Float16*)XW)[idx] : ((const float*)XW)[idx];
            }

        // ---- wait for peers' step-(s-1) H publish: relaxed poll, one acquire ----
        if (s > 0) {
            while (true) {
                int v = __hip_atomic_load(&fl[me], __ATOMIC_RELAXED, __HIP_MEMORY_SCOPE_AGENT);
                if (__all(v >= s)) break;
                __builtin_amdgcn_s_sleep(2);
            }
            __builtin_amdgcn_fence(__ATOMIC_ACQUIRE, "agent");
        }

        const int rp = s & 1;
        u64* Hr = Hbuf + (size_t)(g * 2 + rp) * (NR * DM / 4);
        u64* Hw = Hbuf + (size_t)(g * 2 + (rp ^ 1)) * (NR * DM / 4);

        // A fragments: H rows (agent-scope relaxed loads; fence above ordered them)
        const int m = n;
        const int mz = rs_zero[m];
        half8 afr[16];
#pragma unroll
        for (int kt = 0; kt < 16; kt++) {
            FragU u;
            u.q[0] = __hip_atomic_load(&Hr[m * 128 + kt * 8 + h * 2], __ATOMIC_RELAXED, __HIP_MEMORY_SCOPE_AGENT);
            u.q[1] = __hip_atomic_load(&Hr[m * 128 + kt * 8 + h * 2 + 1], __ATOMIC_RELAXED, __HIP_MEMORY_SCOPE_AGENT);
            afr[kt] = mz ? zfrag : u.v;
        }

        floatx4 acc[4] = {};
#pragma unroll
        for (int kt = 0; kt < 16; kt++) {
#pragma unroll
            for (int q = 0; q < 4; q++)
                acc[q] = __builtin_amdgcn_mfma_f32_16x16x32_f16(afr[kt], bf[q][kt], acc[q], 0, 0, 0);
        }

        // gates + state update (keep hn/cn in regs; out-stores deferred)
        float hnv[4], cnv[4];
#pragma unroll
        for (int r = 0; r < 4; r++) {
            int row = h * 4 + r;
            float zi = acc[0][r] + xwv[0][r];
            float zf = acc[1][r] + xwv[1][r];
            float zg = acc[2][r] + xwv[2][r];
            float zo = acc[3][r] + xwv[3][r];
            float cprev = rs_zero[row] ? 0.0f : cc[r];
            float cn = sigf(zf) * cprev + sigf(zi) * tanh_f(zg);
            float hn = sigf(zo) * tanh_f(cn);
            cc[r] = cn; hnv[r] = hn; cnv[r] = cn;
            hstage[w][row][n] = __builtin_bit_cast(u16, (_Float16)hn);
        }

        // pack wave-locally via LDS, publish 8B relaxed stores
        u64 pk = ((const u64*)&hstage[w][0][0])[l];
        __hip_atomic_store(&Hw[(size_t)(l >> 2) * 128 + c * 4 + (l & 3)], pk, __ATOMIC_RELAXED, __HIP_MEMORY_SCOPE_AGENT);

        __syncthreads();  // all threads' H stores drained (vmcnt0 at barrier)
        if (tid == 0)
            __hip_atomic_store(&fl[wid_in_g], s + 1, __ATOMIC_RELEASE, __HIP_MEMORY_SCOPE_AGENT);

        // ---- out stores: off the critical path, overlap with peers' spin ----
#pragma unroll
        for (int r = 0; r < 4; r++) {
            if (act[r]) {
                size_t oo = (size_t)tr[r] * DM + d;
                outH[oo] = hnv[r]; outC[oo] = cnv[r]; outH2[oo] = hnv[r];
            }
        }
    }
}

extern "C" void kernel_launch(void* const* d_in, const int* in_sizes, int n_in,
                              void* d_out, int out_size, void* d_ws, size_t ws_size,
                              hipStream_t stream) {
    const float* inputs = (const float*)d_in[0];
    const void* terms = d_in[1];
    const float* c0 = (const float*)d_in[2];
    const float* h0 = (const float*)d_in[3];
    const float* Wx = (const float*)d_in[4];
    const float* Wh = (const float*)d_in[5];
    const float* bias = (const float*)d_in[6];
    float* out = (float*)d_out;

    size_t szXWf = (size_t)T_LEN * NC * 4;
    size_t szXWh = (size_t)T_LEN * NC * 2;
    size_t rest = ((size_t)T_LEN * DM * 2 + 256) + 2 * ((size_t)DM * NC * 2 + 256)
                + 2 * ((size_t)(T_LEN + 2) * 4 + 256)
                + (2ull * NG * NR * DM * 2 + 256) + ((size_t)NG * WPG * 4 + 256) + 512;
    bool xwh = (ws_size < rest + szXWf + 256);

    size_t off = 0;
    auto take = [&](size_t bts) { size_t cur = off; off = (off + bts + 255) & ~(size_t)255; return cur; };
    size_t offXW = take(xwh ? szXWh : szXWf);
    size_t offAin = take((size_t)T_LEN * DM * 2);
    size_t offPX = take((size_t)DM * NC * 2);
    size_t offPW = take((size_t)DM * NC * 2);
    size_t offSS = take((size_t)(T_LEN + 2) * 4);
    size_t offSL = take((size_t)(T_LEN + 2) * 4);
    size_t offH = take(2ull * NG * NR * DM * 2);
    size_t offFL = take((size_t)NG * WPG * 4);
    size_t offME = take(256);
    size_t total = off;

    char* W = (char*)d_ws;
    _Float16* Ain = (_Float16*)(W + offAin);
    half8* PX = (half8*)(W + offPX);
    half8* PWp = (half8*)(W + offPW);
    int* segS = (int*)(W + offSS);
    int* segL = (int*)(W + offSL);
    Meta* meta = (Meta*)(W + offME);
    void* XWp = (void*)(W + offXW);

    size_t zwords = (total - offH) / 4;  // Hbuf + flags + meta contiguous
    zero_kernel<<<256, 256, 0, stream>>>((u32*)(W + offH), zwords);
    pack_f16_kernel<<<(T_LEN * DM / 8 + 255) / 256, 256, 0, stream>>>(inputs, Ain, T_LEN * DM / 8);
    pack_w_kernel<<<512, 256, 0, stream>>>(Wx, PX);
    pack_w_kernel<<<512, 256, 0, stream>>>(Wh, PWp);
    prep_kernel<<<1, 256, 0, stream>>>(terms, h0, segS, segL, meta, (_Float16*)(W + offH));

    dim3 gg(T_LEN / 64, NC / 128);
    if (xwh) {
        xw_gemm_kernel<true><<<gg, 256, 0, stream>>>((const half8*)Ain, (const half8*)PX, bias, XWp);
        scan_kernel<true><<<256, 128, 0, stream>>>((const half8*)PWp, XWp, c0, segS, segL, meta,
                                                   (u64*)(W + offH), (int*)(W + offFL), out);
    } else {
        xw_gemm_kernel<false><<<gg, 256, 0, stream>>>((const half8*)Ain, (const half8*)PX, bias, XWp);
        scan_kernel<false><<<gg.x * 0 + 256, 128, 0, stream>>>((const half8*)PWp, XWp, c0, segS, segL, meta,
                                                    (u64*)(W + offH), (int*)(W + offFL), out);
    }
}

// Round 4
// 3517.716 us; speedup vs baseline: 1.9210x; 1.6108x over previous
//
#include <hip/hip_runtime.h>

typedef _Float16 half8 __attribute__((ext_vector_type(8)));
typedef float floatx4 __attribute__((ext_vector_type(4)));
typedef unsigned long long u64;
typedef unsigned int u32;
typedef unsigned short u16;

#define T_LEN 16384
#define DM 512
#define NC 2048      // 4*DM
#define NG 16        // groups
#define NR 16        // segment rows (batch) per group
#define WPG 16       // workgroups per group
#define WVG 32       // waves per group (= flags per group)

struct Meta { int S; int use_h0; int steps_g[NG]; };

union FragU { u64 q[2]; half8 v; };

__device__ __forceinline__ float sigf(float x) { return 1.0f / (1.0f + __expf(-x)); }
__device__ __forceinline__ float tanh_f(float x) { return 1.0f - 2.0f / (__expf(2.0f * x) + 1.0f); }

// ---------------- zero workspace region ----------------
__global__ void zero_kernel(u32* __restrict__ p, size_t nwords) {
    size_t i = (size_t)blockIdx.x * blockDim.x + threadIdx.x;
    size_t stride = (size_t)gridDim.x * blockDim.x;
    for (; i < nwords; i += stride) p[i] = 0u;
}

// ---------------- f32 -> f16 pack (row-major) ----------------
__global__ void pack_f16_kernel(const float* __restrict__ src, _Float16* __restrict__ dst, int n8) {
    int i = blockIdx.x * blockDim.x + threadIdx.x;
    if (i >= n8) return;
    const floatx4* s = (const floatx4*)src + (size_t)i * 2;
    floatx4 a = s[0], b = s[1];
    half8 o;
    o[0] = (_Float16)a[0]; o[1] = (_Float16)a[1]; o[2] = (_Float16)a[2]; o[3] = (_Float16)a[3];
    o[4] = (_Float16)b[0]; o[5] = (_Float16)b[1]; o[6] = (_Float16)b[2]; o[7] = (_Float16)b[3];
    ((half8*)dst)[i] = o;
}

// ---------------- weight pack to MFMA B-fragment order ----------------
// Logical col for tile tt (= cch*4+q): q*512 + cch*16 + n.  k = kt*32 + h*8 + j.
__global__ __launch_bounds__(256) void pack_w_kernel(const float* __restrict__ src, half8* __restrict__ dst) {
    int wid = blockIdx.x * 4 + (threadIdx.x >> 6);  // 2048 = 128 tiles * 16 kt
    int l = threadIdx.x & 63;
    int tt = wid >> 4, kt = wid & 15;
    int q = tt & 3, cch = tt >> 2;
    int col = q * 512 + cch * 16 + (l & 15);
    int h = l >> 4;
    half8 o;
#pragma unroll
    for (int jj = 0; jj < 8; jj++) o[jj] = (_Float16)src[(size_t)(kt * 32 + h * 8 + jj) * NC + col];
    dst[(tt * 16 + kt) * 64 + l] = o;
}

// ---------------- prep: term dtype detect, segment extraction, chains ----------------
__global__ void prep_kernel(const void* __restrict__ termraw, const float* __restrict__ h0,
                            int* __restrict__ seg_start, int* __restrict__ seg_len,
                            Meta* __restrict__ meta, _Float16* __restrict__ Hbuf) {
    __shared__ int cnts[256], offs[256];
    __shared__ int nzm, oddnz, totS;
    __shared__ int chain[256];
    int tid = threadIdx.x;
    if (tid == 0) { nzm = 0; oddnz = 0; }
    __syncthreads();
    const unsigned char* tb = (const unsigned char*)termraw;
    const int* ti = (const int*)termraw;
    int lm = 0;
    for (int i = tid; i < T_LEN; i += 256) {
        if (tb[i]) {
            int p = i & 3;
            if (p == 1 || p == 2) lm |= 1;
            else if (p == 3) lm |= 2;
            else lm |= 4;
        }
    }
    if (lm) atomicOr(&nzm, lm);
    __syncthreads();
    int mm = nzm;
    int bytemode = (mm & 1) ? 1 : 0;
    int floatmode = (!bytemode && (mm & 2)) ? 1 : 0;
    int lo = 0;
    if (!bytemode && !floatmode) {
        for (int k2 = 2 * tid + 1; k2 < T_LEN; k2 += 512) if (ti[k2]) lo = 1;
    }
    if (lo) atomicOr(&oddnz, 1);
    __syncthreads();
    int i64mode = (!bytemode && !floatmode && oddnz == 0 && (mm & 4)) ? 1 : 0;
    const float* tf = (const float*)termraw;

    auto termAt = [&](int t) -> int {
        if (bytemode) return tb[t] != 0;
        if (floatmode) return tf[t] != 0.0f;
        if (i64mode) return (ti[2 * t] != 0) || (ti[2 * t + 1] != 0);
        return ti[t] != 0;
    };

    int base = tid * 64;
    int cnt = 0;
    for (int k = 0; k < 64; k++) {
        int t = base + k;
        if (t == 0 || termAt(t)) cnt++;
    }
    cnts[tid] = cnt;
    __syncthreads();
    if (tid == 0) {
        int a = 0;
        for (int i = 0; i < 256; i++) { offs[i] = a; a += cnts[i]; }
        totS = a;
        meta->S = a;
    }
    __syncthreads();
    int S = totS;
    {
        int o = offs[tid];
        for (int k = 0; k < 64; k++) {
            int t = base + k;
            if (t == 0 || termAt(t)) seg_start[o++] = t;
        }
    }
    __syncthreads();
    for (int i = tid; i < S; i += 256)
        seg_len[i] = ((i + 1 < S) ? seg_start[i + 1] : T_LEN) - seg_start[i];
    __syncthreads();
    {
        int g = tid >> 4, r = tid & 15;
        int tot = 0;
        for (int i = g + 16 * r; i < S; i += 256) tot += seg_len[i];
        chain[tid] = tot;
    }
    __syncthreads();
    if (tid < NG) {
        int mx = 0;
        for (int r = 0; r < 16; r++) mx = max(mx, chain[tid * 16 + r]);
        meta->steps_g[tid] = mx;
    }
    int u = termAt(0);
    if (tid == 0) meta->use_h0 = !u;
    if (!u) {
        for (int d2 = tid; d2 < DM; d2 += 256) Hbuf[d2] = (_Float16)h0[d2];
    }
}

// ---------------- XW = inputs @ Wx + b (fp16 MFMA, packed-col order) ----------------
template <bool XWH>
__global__ __launch_bounds__(256) void xw_gemm_kernel(const half8* __restrict__ A, const half8* __restrict__ B,
                                                      const float* __restrict__ bias, void* __restrict__ XW) {
    int bx = blockIdx.x, by = blockIdx.y;
    int w = threadIdx.x >> 6, l = threadIdx.x & 63;
    int mbase = bx * 64 + w * 16;
    int h = l >> 4, n = l & 15;
    floatx4 acc[8] = {};
    int arow = mbase + n;
#pragma unroll
    for (int kt = 0; kt < 16; kt++) {
        half8 a = A[(size_t)arow * 64 + kt * 4 + h];
#pragma unroll
        for (int nt = 0; nt < 8; nt++)
            acc[nt] = __builtin_amdgcn_mfma_f32_16x16x32_f16(a, B[((by * 8 + nt) * 16 + kt) * 64 + l], acc[nt], 0, 0, 0);
    }
#pragma unroll
    for (int nt = 0; nt < 8; nt++) {
        int tt = by * 8 + nt, q = tt & 3, cch = tt >> 2;
        float bv = bias[q * 512 + cch * 16 + n];
#pragma unroll
        for (int r = 0; r < 4; r++) {
            int row = mbase + h * 4 + r;
            float v = acc[nt][r] + bv;
            size_t idx = (size_t)row * NC + tt * 16 + n;
            if (XWH) ((_Float16*)XW)[idx] = (_Float16)v;
            else ((float*)XW)[idx] = v;
        }
    }
}

// ---------------- per-thread segment tracker (registers only, no barriers) ----------------
struct Trk { int seg, t0, s0, end, active; };

__device__ __forceinline__ void trk_init(Trk& k, int row, int g, int S,
                                         const int* __restrict__ ss, const int* __restrict__ sl) {
    int seg = g + 16 * row;
    k.seg = seg;
    if (seg < S) { k.t0 = ss[seg]; k.s0 = 0; k.end = sl[seg]; k.active = 1; }
    else { k.t0 = 0; k.s0 = 0; k.end = 0x7fffffff; k.active = 0; }
}

__device__ __forceinline__ int trk_step(Trk& k, int s, int S,
                                        const int* __restrict__ ss, const int* __restrict__ sl, int& t_out) {
    int z = !k.active;
    if (s > 0 && k.active && s == k.end) {
        int seg = k.seg + 256;
        if (seg < S) { k.seg = seg; k.t0 = ss[seg]; k.s0 = s; k.end = s + sl[seg]; z = 1; }
        else { k.active = 0; z = 1; }
    }
    t_out = k.active ? (k.t0 + (s - k.s0)) : 0;
    return z;
}

// ---------------- recurrent scan v4: fence-free, barrier-free step loop ----------------
// v3 bug fix: the hstage u16-writes -> u64-read regroup had NO ordering once
// __syncthreads was removed; TBAA says u16 stores don't alias u64 loads, so the
// compiler could hoist the ds_read above the ds_writes -> published stale LDS
// (step 0 = uninitialized = NaN f16 patterns). Fix: full compiler memory barrier
// + s_waitcnt lgkmcnt(0) + sched_barrier(0) between the writes and the read.
template <bool XWH>
__global__ __launch_bounds__(128, 1) void scan_kernel(
    const half8* __restrict__ PW, const void* __restrict__ XW,
    const float* __restrict__ c0,
    const int* __restrict__ seg_start, const int* __restrict__ seg_len,
    const Meta* __restrict__ meta,
    u64* __restrict__ Hbuf, int* __restrict__ flags,
    float* __restrict__ out) {
    const int b = blockIdx.x;
    const int g = (b & 7) * 2 + (b >> 7);   // XCD-local groups (perf hint only)
    const int jj = (b >> 3) & 15;
    const int tid = threadIdx.x;
    const int w = tid >> 6, l = tid & 63;
    const int c = jj * 2 + w;               // dim chunk 0..31 (16 dims each)
    const int S = meta->S;
    const int steps = meta->steps_g[g];
    if (steps <= 0) return;
    const int use_h0 = meta->use_h0;
    const int n = l & 15, h = l >> 4;
    const int d = c * 16 + n;

    __shared__ __align__(16) u16 hstage[2][NR][16];

    // resident Wh B-fragments: 4 gate tiles x 16 k-steps
    half8 bf[4][16];
#pragma unroll
    for (int q = 0; q < 4; q++)
#pragma unroll
        for (int kt = 0; kt < 16; kt++)
            bf[q][kt] = PW[((c * 4 + q) * 16 + kt) * 64 + l];

    // per-thread trackers: row n (A-frag zero mask) + compute rows h*4+0..3
    Trk trkM; trk_init(trkM, n, g, S, seg_start, seg_len);
    Trk trk[4];
#pragma unroll
    for (int r = 0; r < 4; r++) trk_init(trk[r], h * 4 + r, g, S, seg_start, seg_len);

    float cc[4];
#pragma unroll
    for (int r = 0; r < 4; r++) {
        int row = h * 4 + r;
        cc[r] = (g == 0 && row == 0 && use_h0) ? c0[d] : 0.0f;
    }

    FragU zu; zu.q[0] = 0; zu.q[1] = 0;
    const half8 zfrag = zu.v;

    int* fl = flags + g * WVG;
    const int wfid = jj * 2 + w;   // wave id within group 0..31 (unique per wave)
    const int pollidx = l & 31;

    float* outH = out;
    float* outC = out + (size_t)T_LEN * DM;
    float* outH2 = out + 2 * (size_t)T_LEN * DM;

    for (int s = 0; s < steps; ++s) {
        // ---- per-thread rs state for step s ----
        int tdump;
        const int zM = trk_step(trkM, s, S, seg_start, seg_len, tdump);
        int zz[4], tr[4], act[4];
#pragma unroll
        for (int r = 0; r < 4; r++) {
            zz[r] = trk_step(trk[r], s, S, seg_start, seg_len, tr[r]);
            act[r] = trk[r].active;
        }

        // ---- issue XW gather for step s (in flight during the spin) ----
        float xwv[4][4];
#pragma unroll
        for (int q = 0; q < 4; q++)
#pragma unroll
            for (int r = 0; r < 4; r++) {
                size_t idx = (size_t)tr[r] * NC + (c * 4 + q) * 16 + n;
                xwv[q][r] = XWH ? (float)((const _Float16*)XW)[idx] : ((const float*)XW)[idx];
            }

        // ---- wait for peers' step-(s-1) H publish: relaxed poll, compiler barrier ----
        if (s > 0) {
            while (true) {
                int v = __hip_atomic_load(&fl[pollidx], __ATOMIC_RELAXED, __HIP_MEMORY_SCOPE_AGENT);
                if (__all(v >= s)) break;
                __builtin_amdgcn_s_sleep(2);
            }
            asm volatile("" ::: "memory");  // compiler ordering only; data moves via sc1 atomics
        }

        const int rp = s & 1;
        u64* Hr = Hbuf + (size_t)(g * 2 + rp) * (NR * DM / 4);
        u64* Hw = Hbuf + (size_t)(g * 2 + (rp ^ 1)) * (NR * DM / 4);

        // A fragments: H rows (sc1 relaxed loads; in-order issue after the poll)
        const int m = n;
        half8 afr[16];
#pragma unroll
        for (int kt = 0; kt < 16; kt++) {
            FragU u;
            u.q[0] = __hip_atomic_load(&Hr[m * 128 + kt * 8 + h * 2], __ATOMIC_RELAXED, __HIP_MEMORY_SCOPE_AGENT);
            u.q[1] = __hip_atomic_load(&Hr[m * 128 + kt * 8 + h * 2 + 1], __ATOMIC_RELAXED, __HIP_MEMORY_SCOPE_AGENT);
            afr[kt] = zM ? zfrag : u.v;
        }

        floatx4 acc[4] = {};
#pragma unroll
        for (int kt = 0; kt < 16; kt++) {
#pragma unroll
            for (int q = 0; q < 4; q++)
                acc[q] = __builtin_amdgcn_mfma_f32_16x16x32_f16(afr[kt], bf[q][kt], acc[q], 0, 0, 0);
        }

        // gates + state update
        float hnv[4], cnv[4];
#pragma unroll
        for (int r = 0; r < 4; r++) {
            float zi = acc[0][r] + xwv[0][r];
            float zf = acc[1][r] + xwv[1][r];
            float zg = acc[2][r] + xwv[2][r];
            float zo = acc[3][r] + xwv[3][r];
            float cprev = zz[r] ? 0.0f : cc[r];
            float cn = sigf(zf) * cprev + sigf(zi) * tanh_f(zg);
            float hn = sigf(zo) * tanh_f(cn);
            cc[r] = cn; hnv[r] = hn; cnv[r] = cn;
            hstage[w][h * 4 + r][n] = __builtin_bit_cast(u16, (_Float16)hn);
        }

        // ---- wave-local regroup via LDS; MUST order writes->read explicitly ----
        asm volatile("s_waitcnt lgkmcnt(0)" ::: "memory");  // HW-complete ds_writes + defeat TBAA reordering
        __builtin_amdgcn_sched_barrier(0);
        u64 pk = ((const u64*)&hstage[w][0][0])[l];
        __hip_atomic_store(&Hw[(size_t)(l >> 2) * 128 + c * 4 + (l & 3)], pk, __ATOMIC_RELAXED, __HIP_MEMORY_SCOPE_AGENT);

        // drain THIS wave's stores to the coherence point, then publish wave flag
        asm volatile("s_waitcnt vmcnt(0)" ::: "memory");
        if (l == 0)
            __hip_atomic_store(&fl[wfid], s + 1, __ATOMIC_RELAXED, __HIP_MEMORY_SCOPE_AGENT);

        // ---- out stores: off the critical path (drained a full step later) ----
#pragma unroll
        for (int r = 0; r < 4; r++) {
            if (act[r]) {
                size_t oo = (size_t)tr[r] * DM + d;
                outH[oo] = hnv[r]; outC[oo] = cnv[r]; outH2[oo] = hnv[r];
            }
        }
    }
}

extern "C" void kernel_launch(void* const* d_in, const int* in_sizes, int n_in,
                              void* d_out, int out_size, void* d_ws, size_t ws_size,
                              hipStream_t stream) {
    const float* inputs = (const float*)d_in[0];
    const void* terms = d_in[1];
    const float* c0 = (const float*)d_in[2];
    const float* h0 = (const float*)d_in[3];
    const float* Wx = (const float*)d_in[4];
    const float* Wh = (const float*)d_in[5];
    const float* bias = (const float*)d_in[6];
    float* out = (float*)d_out;

    size_t szXWf = (size_t)T_LEN * NC * 4;
    size_t szXWh = (size_t)T_LEN * NC * 2;
    size_t rest = ((size_t)T_LEN * DM * 2 + 256) + 2 * ((size_t)DM * NC * 2 + 256)
                + 2 * ((size_t)(T_LEN + 2) * 4 + 256)
                + (2ull * NG * NR * DM * 2 + 256) + ((size_t)NG * WVG * 4 + 256) + 512;
    bool xwh = (ws_size < rest + szXWf + 256);

    size_t off = 0;
    auto take = [&](size_t bts) { size_t cur = off; off = (off + bts + 255) & ~(size_t)255; return cur; };
    size_t offXW = take(xwh ? szXWh : szXWf);
    size_t offAin = take((size_t)T_LEN * DM * 2);
    size_t offPX = take((size_t)DM * NC * 2);
    size_t offPW = take((size_t)DM * NC * 2);
    size_t offSS = take((size_t)(T_LEN + 2) * 4);
    size_t offSL = take((size_t)(T_LEN + 2) * 4);
    size_t offH = take(2ull * NG * NR * DM * 2);
    size_t offFL = take((size_t)NG * WVG * 4);
    size_t offME = take(256);
    size_t total = off;

    char* W = (char*)d_ws;
    _Float16* Ain = (_Float16*)(W + offAin);
    half8* PX = (half8*)(W + offPX);
    half8* PWp = (half8*)(W + offPW);
    int* segS = (int*)(W + offSS);
    int* segL = (int*)(W + offSL);
    Meta* meta = (Meta*)(W + offME);
    void* XWp = (void*)(W + offXW);

    size_t zwords = (total - offH) / 4;  // Hbuf + flags + meta contiguous
    zero_kernel<<<256, 256, 0, stream>>>((u32*)(W + offH), zwords);
    pack_f16_kernel<<<(T_LEN * DM / 8 + 255) / 256, 256, 0, stream>>>(inputs, Ain, T_LEN * DM / 8);
    pack_w_kernel<<<512, 256, 0, stream>>>(Wx, PX);
    pack_w_kernel<<<512, 256, 0, stream>>>(Wh, PWp);
    prep_kernel<<<1, 256, 0, stream>>>(terms, h0, segS, segL, meta, (_Float16*)(W + offH));

    dim3 gg(T_LEN / 64, NC / 128);
    if (xwh) {
        xw_gemm_kernel<true><<<gg, 256, 0, stream>>>((const half8*)Ain, (const half8*)PX, bias, XWp);
        scan_kernel<true><<<256, 128, 0, stream>>>((const half8*)PWp, XWp, c0, segS, segL, meta,
                                                   (u64*)(W + offH), (int*)(W + offFL), out);
    } else {
        xw_gemm_kernel<false><<<gg, 256, 0, stream>>>((const half8*)Ain, (const half8*)PX, bias, XWp);
        scan_kernel<false><<<256, 128, 0, stream>>>((const half8*)PWp, XWp, c0, segS, segL, meta,
                                                    (u64*)(W + offH), (int*)(W + offFL), out);
    }
}

// Round 6
// 2086.144 us; speedup vs baseline: 3.2392x; 1.6862x over previous
//
#include <hip/hip_runtime.h>

typedef _Float16 half8 __attribute__((ext_vector_type(8)));
typedef float floatx4 __attribute__((ext_vector_type(4)));
typedef unsigned int u32x4 __attribute__((ext_vector_type(4)));
typedef unsigned long long u64;
typedef unsigned int u32;
typedef unsigned short u16;

#define T_LEN 16384
#define DM 512
#define NC 2048      // 4*DM
#define NG 16        // groups
#define NR 16        // segment rows (batch) per group
#define WPG 16       // workgroups per group
#define WVG 32       // waves per group (= flags per group)

struct Meta { int S; int use_h0; int steps_g[NG]; };

union FragU { u64 q[2]; u32x4 r; half8 v; };

__device__ __forceinline__ float sigf(float x) { return 1.0f / (1.0f + __expf(-x)); }
__device__ __forceinline__ float tanh_f(float x) { return 1.0f - 2.0f / (__expf(2.0f * x) + 1.0f); }

// ---------------- zero workspace region ----------------
__global__ void zero_kernel(u32* __restrict__ p, size_t nwords) {
    size_t i = (size_t)blockIdx.x * blockDim.x + threadIdx.x;
    size_t stride = (size_t)gridDim.x * blockDim.x;
    for (; i < nwords; i += stride) p[i] = 0u;
}

// ---------------- f32 -> f16 pack (row-major) ----------------
__global__ void pack_f16_kernel(const float* __restrict__ src, _Float16* __restrict__ dst, int n8) {
    int i = blockIdx.x * blockDim.x + threadIdx.x;
    if (i >= n8) return;
    const floatx4* s = (const floatx4*)src + (size_t)i * 2;
    floatx4 a = s[0], b = s[1];
    half8 o;
    o[0] = (_Float16)a[0]; o[1] = (_Float16)a[1]; o[2] = (_Float16)a[2]; o[3] = (_Float16)a[3];
    o[4] = (_Float16)b[0]; o[5] = (_Float16)b[1]; o[6] = (_Float16)b[2]; o[7] = (_Float16)b[3];
    ((half8*)dst)[i] = o;
}

// ---------------- weight pack to MFMA B-fragment order ----------------
__global__ __launch_bounds__(256) void pack_w_kernel(const float* __restrict__ src, half8* __restrict__ dst) {
    int wid = blockIdx.x * 4 + (threadIdx.x >> 6);  // 2048 = 128 tiles * 16 kt
    int l = threadIdx.x & 63;
    int tt = wid >> 4, kt = wid & 15;
    int q = tt & 3, cch = tt >> 2;
    int col = q * 512 + cch * 16 + (l & 15);
    int h = l >> 4;
    half8 o;
#pragma unroll
    for (int jj = 0; jj < 8; jj++) o[jj] = (_Float16)src[(size_t)(kt * 32 + h * 8 + jj) * NC + col];
    dst[(tt * 16 + kt) * 64 + l] = o;
}

// ---------------- prep: term dtype detect, segment extraction, chains ----------------
__global__ void prep_kernel(const void* __restrict__ termraw, const float* __restrict__ h0,
                            int* __restrict__ seg_start, int* __restrict__ seg_len,
                            Meta* __restrict__ meta, _Float16* __restrict__ Hbuf) {
    __shared__ int cnts[256], offs[256];
    __shared__ int nzm, oddnz, totS;
    __shared__ int chain[256];
    int tid = threadIdx.x;
    if (tid == 0) { nzm = 0; oddnz = 0; }
    __syncthreads();
    const unsigned char* tb = (const unsigned char*)termraw;
    const int* ti = (const int*)termraw;
    int lm = 0;
    for (int i = tid; i < T_LEN; i += 256) {
        if (tb[i]) {
            int p = i & 3;
            if (p == 1 || p == 2) lm |= 1;
            else if (p == 3) lm |= 2;
            else lm |= 4;
        }
    }
    if (lm) atomicOr(&nzm, lm);
    __syncthreads();
    int mm = nzm;
    int bytemode = (mm & 1) ? 1 : 0;
    int floatmode = (!bytemode && (mm & 2)) ? 1 : 0;
    int lo = 0;
    if (!bytemode && !floatmode) {
        for (int k2 = 2 * tid + 1; k2 < T_LEN; k2 += 512) if (ti[k2]) lo = 1;
    }
    if (lo) atomicOr(&oddnz, 1);
    __syncthreads();
    int i64mode = (!bytemode && !floatmode && oddnz == 0 && (mm & 4)) ? 1 : 0;
    const float* tf = (const float*)termraw;

    auto termAt = [&](int t) -> int {
        if (bytemode) return tb[t] != 0;
        if (floatmode) return tf[t] != 0.0f;
        if (i64mode) return (ti[2 * t] != 0) || (ti[2 * t + 1] != 0);
        return ti[t] != 0;
    };

    int base = tid * 64;
    int cnt = 0;
    for (int k = 0; k < 64; k++) {
        int t = base + k;
        if (t == 0 || termAt(t)) cnt++;
    }
    cnts[tid] = cnt;
    __syncthreads();
    if (tid == 0) {
        int a = 0;
        for (int i = 0; i < 256; i++) { offs[i] = a; a += cnts[i]; }
        totS = a;
        meta->S = a;
    }
    __syncthreads();
    int S = totS;
    {
        int o = offs[tid];
        for (int k = 0; k < 64; k++) {
            int t = base + k;
            if (t == 0 || termAt(t)) seg_start[o++] = t;
        }
    }
    __syncthreads();
    for (int i = tid; i < S; i += 256)
        seg_len[i] = ((i + 1 < S) ? seg_start[i + 1] : T_LEN) - seg_start[i];
    __syncthreads();
    {
        int g = tid >> 4, r = tid & 15;
        int tot = 0;
        for (int i = g + 16 * r; i < S; i += 256) tot += seg_len[i];
        chain[tid] = tot;
    }
    __syncthreads();
    if (tid < NG) {
        int mx = 0;
        for (int r = 0; r < 16; r++) mx = max(mx, chain[tid * 16 + r]);
        meta->steps_g[tid] = mx;
    }
    int u = termAt(0);
    if (tid == 0) meta->use_h0 = !u;
    if (!u) {
        // h0 seed into group0/parity0/row0, coalesced layout Hb[kt][hh][m=0][j]
        for (int d2 = tid; d2 < DM; d2 += 256)
            Hbuf[(d2 >> 3) * 128 + (d2 & 7)] = (_Float16)h0[d2];
    }
}

// ---------------- XW = inputs @ Wx + b (fp16 MFMA, packed-col order, fp16 out) ----------------
__global__ __launch_bounds__(256) void xw_gemm_kernel(const half8* __restrict__ A, const half8* __restrict__ B,
                                                      const float* __restrict__ bias, _Float16* __restrict__ XW) {
    int bx = blockIdx.x, by = blockIdx.y;
    int w = threadIdx.x >> 6, l = threadIdx.x & 63;
    int mbase = bx * 64 + w * 16;
    int h = l >> 4, n = l & 15;
    floatx4 acc[8] = {};
    int arow = mbase + n;
#pragma unroll
    for (int kt = 0; kt < 16; kt++) {
        half8 a = A[(size_t)arow * 64 + kt * 4 + h];
#pragma unroll
        for (int nt = 0; nt < 8; nt++)
            acc[nt] = __builtin_amdgcn_mfma_f32_16x16x32_f16(a, B[((by * 8 + nt) * 16 + kt) * 64 + l], acc[nt], 0, 0, 0);
    }
#pragma unroll
    for (int nt = 0; nt < 8; nt++) {
        int tt = by * 8 + nt, q = tt & 3, cch = tt >> 2;
        float bv = bias[q * 512 + cch * 16 + n];
#pragma unroll
        for (int r = 0; r < 4; r++) {
            int row = mbase + h * 4 + r;
            XW[(size_t)row * NC + tt * 16 + n] = (_Float16)(acc[nt][r] + bv);
        }
    }
}

// ---------------- per-thread segment tracker ----------------
struct Trk { int seg, t0, s0, end, active; };

__device__ __forceinline__ void trk_init(Trk& k, int row, int g, int S,
                                         const int* __restrict__ ss, const int* __restrict__ sl) {
    int seg = g + 16 * row;
    k.seg = seg;
    if (seg < S) { k.t0 = ss[seg]; k.s0 = 0; k.end = sl[seg]; k.active = 1; }
    else { k.t0 = 0; k.s0 = 0; k.end = 0x7fffffff; k.active = 0; }
}

__device__ __forceinline__ int trk_step(Trk& k, int s, int S,
                                        const int* __restrict__ ss, const int* __restrict__ sl, int& t_out) {
    int z = !k.active;
    if (s > 0 && k.active && s == k.end) {
        int seg = k.seg + 256;
        if (seg < S) { k.seg = seg; k.t0 = ss[seg]; k.s0 = s; k.end = s + sl[seg]; z = 1; }
        else { k.active = 0; z = 1; }
    }
    t_out = k.active ? (k.t0 + (s - k.s0)) : 0;
    return z;
}

// ---------------- recurrent scan v6: R4 protocol + coalesced H + dwordx4 sc1 burst
//                  + fp16 XW with one-step-lookahead prefetch ----------------
// H layout (per group, per parity): Hb[kt][h][m] of half8 — a wave's per-kt A-fragment
// read is one contiguous 1KB block -> one global_load_dwordx4 sc1 per (kt, lane).
__global__ __launch_bounds__(128, 1) void scan_kernel(
    const half8* __restrict__ PW, const _Float16* __restrict__ XW,
    const float* __restrict__ c0,
    const int* __restrict__ seg_start, const int* __restrict__ seg_len,
    const Meta* __restrict__ meta,
    u64* __restrict__ Hbuf, int* __restrict__ flags,
    float* __restrict__ out) {
    const int b = blockIdx.x;
    const int g = (b & 7) * 2 + (b >> 7);   // XCD-local groups (perf hint only)
    const int jj = (b >> 3) & 15;
    const int tid = threadIdx.x;
    const int w = tid >> 6, l = tid & 63;
    const int c = jj * 2 + w;               // dim chunk 0..31 (16 dims each)
    const int S = meta->S;
    const int steps = meta->steps_g[g];
    if (steps <= 0) return;
    const int use_h0 = meta->use_h0;
    const int n = l & 15, h = l >> 4;
    const int d = c * 16 + n;

    __shared__ __align__(16) u16 hstage[2][NR][16];

    // resident Wh B-fragments, pinned against rematerialization (R4: VGPR=180 showed reload)
    half8 bf[4][16];
#pragma unroll
    for (int q = 0; q < 4; q++)
#pragma unroll
        for (int kt = 0; kt < 16; kt++) {
            bf[q][kt] = PW[((c * 4 + q) * 16 + kt) * 64 + l];
            asm volatile("" : "+v"(bf[q][kt]));
        }

    Trk trkM; trk_init(trkM, n, g, S, seg_start, seg_len);
    Trk trk[4];
#pragma unroll
    for (int r = 0; r < 4; r++) trk_init(trk[r], h * 4 + r, g, S, seg_start, seg_len);

    float cc[4];
#pragma unroll
    for (int r = 0; r < 4; r++) {
        int row = h * 4 + r;
        cc[r] = (g == 0 && row == 0 && use_h0) ? c0[d] : 0.0f;
    }

    FragU zu; zu.q[0] = 0; zu.q[1] = 0;
    const half8 zfrag = zu.v;

    int* fl = flags + g * WVG;
    const int wfid = jj * 2 + w;
    const int pollidx = l & 31;

    float* outH = out;
    float* outC = out + (size_t)T_LEN * DM;
    float* outH2 = out + 2 * (size_t)T_LEN * DM;

    // producer store coords (coalesced layout): lane -> (b2, m2, half)
    const int b2 = l >> 5, m2 = (l >> 1) & 15, half = l & 1;
    const int ktc = c >> 1, hhp = (c & 1) * 2 + b2;
    const int ldsIdx = m2 * 4 + b2 * 2 + half;          // u64 index into hstage[w]
    const size_t hwIdx = (size_t)(ktc * 4 + hhp) * 32 + m2 * 2 + half;

    // ---- prologue: step-0 tracker state + XW prefetch ----
    int tdump;
    int zM = trk_step(trkM, 0, S, seg_start, seg_len, tdump);
    int zz[4], tr[4], act[4];
#pragma unroll
    for (int r = 0; r < 4; r++) {
        zz[r] = trk_step(trk[r], 0, S, seg_start, seg_len, tr[r]);
        act[r] = trk[r].active;
    }
    float xwv[4][4];
#pragma unroll
    for (int q = 0; q < 4; q++)
#pragma unroll
        for (int r = 0; r < 4; r++)
            xwv[q][r] = (float)XW[(size_t)tr[r] * NC + (c * 4 + q) * 16 + n];

    for (int s = 0; s < steps; ++s) {
        // ---- wait for peers' step-(s-1) publish (proven agent protocol) ----
        if (s > 0) {
            while (true) {
                int v = __hip_atomic_load(&fl[pollidx], __ATOMIC_RELAXED, __HIP_MEMORY_SCOPE_AGENT);
                if (__all(v >= s)) break;
                __builtin_amdgcn_s_sleep(1);
            }
            asm volatile("" ::: "memory");
        }

        const int rp = s & 1;
        u64* Hr = Hbuf + (size_t)(g * 2 + rp) * (NR * DM / 4);
        u64* Hw = Hbuf + (size_t)(g * 2 + (rp ^ 1)) * (NR * DM / 4);

        // ---- A-fragment burst: 16 x dwordx4 sc1 (L1/L2-bypassing, one txn/line) ----
        const int m = n;
        u32x4 raw[16];
#pragma unroll
        for (int kt = 0; kt < 16; kt++) {
            const void* ap = (const char*)Hr + (((size_t)kt * 64 + h * 16 + m) << 4);
            asm volatile("global_load_dwordx4 %0, %1, off sc1" : "=v"(raw[kt]) : "v"(ap) : "memory");
        }
        asm volatile("s_waitcnt vmcnt(0)" ::: "memory");
        __builtin_amdgcn_sched_barrier(0);
        half8 afr[16];
#pragma unroll
        for (int kt = 0; kt < 16; kt++) {
            FragU u; u.r = raw[kt];
            afr[kt] = zM ? zfrag : u.v;
        }

        floatx4 acc[4] = {};
#pragma unroll
        for (int kt = 0; kt < 16; kt++) {
#pragma unroll
            for (int q = 0; q < 4; q++)
                acc[q] = __builtin_amdgcn_mfma_f32_16x16x32_f16(afr[kt], bf[q][kt], acc[q], 0, 0, 0);
        }

        float hnv[4], cnv[4];
#pragma unroll
        for (int r = 0; r < 4; r++) {
            float zi = acc[0][r] + xwv[0][r];
            float zf = acc[1][r] + xwv[1][r];
            float zg = acc[2][r] + xwv[2][r];
            float zo = acc[3][r] + xwv[3][r];
            float cprev = zz[r] ? 0.0f : cc[r];
            float cn = sigf(zf) * cprev + sigf(zi) * tanh_f(zg);
            float hn = sigf(zo) * tanh_f(cn);
            cc[r] = cn; hnv[r] = hn; cnv[r] = cn;
            hstage[w][h * 4 + r][n] = __builtin_bit_cast(u16, (_Float16)hn);
        }

        // wave-local regroup via LDS; order u16-writes -> u64-read explicitly (R3 lesson)
        asm volatile("s_waitcnt lgkmcnt(0)" ::: "memory");
        __builtin_amdgcn_sched_barrier(0);
        u64 pk = ((const u64*)&hstage[w][0][0])[ldsIdx];
        __hip_atomic_store(&Hw[hwIdx], pk, __ATOMIC_RELAXED, __HIP_MEMORY_SCOPE_AGENT);

        // drain this wave's H store, then publish wave flag
        asm volatile("s_waitcnt vmcnt(0)" ::: "memory");
        if (l == 0)
            __hip_atomic_store(&fl[wfid], s + 1, __ATOMIC_RELAXED, __HIP_MEMORY_SCOPE_AGENT);

        // ---- post-flag: save current coords, advance trackers, prefetch XW(s+1) ----
        int otr[4], oact[4];
#pragma unroll
        for (int r = 0; r < 4; r++) { otr[r] = tr[r]; oact[r] = act[r]; }

        zM = trk_step(trkM, s + 1, S, seg_start, seg_len, tdump);
#pragma unroll
        for (int r = 0; r < 4; r++) {
            zz[r] = trk_step(trk[r], s + 1, S, seg_start, seg_len, tr[r]);
            act[r] = trk[r].active;
        }
#pragma unroll
        for (int q = 0; q < 4; q++)
#pragma unroll
            for (int r = 0; r < 4; r++)
                xwv[q][r] = (float)XW[(size_t)tr[r] * NC + (c * 4 + q) * 16 + n];

        // out stores for step s (off the critical path)
#pragma unroll
        for (int r = 0; r < 4; r++) {
            if (oact[r]) {
                size_t oo = (size_t)otr[r] * DM + d;
                outH[oo] = hnv[r]; outC[oo] = cnv[r]; outH2[oo] = hnv[r];
            }
        }
    }
}

extern "C" void kernel_launch(void* const* d_in, const int* in_sizes, int n_in,
                              void* d_out, int out_size, void* d_ws, size_t ws_size,
                              hipStream_t stream) {
    const float* inputs = (const float*)d_in[0];
    const void* terms = d_in[1];
    const float* c0 = (const float*)d_in[2];
    const float* h0 = (const float*)d_in[3];
    const float* Wx = (const float*)d_in[4];
    const float* Wh = (const float*)d_in[5];
    const float* bias = (const float*)d_in[6];
    float* out = (float*)d_out;

    size_t off = 0;
    auto take = [&](size_t bts) { size_t cur = off; off = (off + bts + 255) & ~(size_t)255; return cur; };
    size_t offXW = take((size_t)T_LEN * NC * 2);       // fp16 XW always
    size_t offAin = take((size_t)T_LEN * DM * 2);
    size_t offPX = take((size_t)DM * NC * 2);
    size_t offPW = take((size_t)DM * NC * 2);
    size_t offSS = take((size_t)(T_LEN + 2) * 4);
    size_t offSL = take((size_t)(T_LEN + 2) * 4);
    size_t offH = take(2ull * NG * NR * DM * 2);
    size_t offFL = take((size_t)NG * WVG * 4);
    size_t offME = take(256);
    size_t total = off;
    (void)ws_size;

    char* W = (char*)d_ws;
    _Float16* Ain = (_Float16*)(W + offAin);
    half8* PX = (half8*)(W + offPX);
    half8* PWp = (half8*)(W + offPW);
    int* segS = (int*)(W + offSS);
    int* segL = (int*)(W + offSL);
    Meta* meta = (Meta*)(W + offME);
    _Float16* XWp = (_Float16*)(W + offXW);

    size_t zwords = (total - offH) / 4;  // Hbuf + flags + meta contiguous
    zero_kernel<<<256, 256, 0, stream>>>((u32*)(W + offH), zwords);
    pack_f16_kernel<<<(T_LEN * DM / 8 + 255) / 256, 256, 0, stream>>>(inputs, Ain, T_LEN * DM / 8);
    pack_w_kernel<<<512, 256, 0, stream>>>(Wx, PX);
    pack_w_kernel<<<512, 256, 0, stream>>>(Wh, PWp);
    prep_kernel<<<1, 256, 0, stream>>>(terms, h0, segS, segL, meta, (_Float16*)(W + offH));

    dim3 gg(T_LEN / 64, NC / 128);
    xw_gemm_kernel<<<gg, 256, 0, stream>>>((const half8*)Ain, (const half8*)PX, bias, XWp);
    scan_kernel<<<256, 128, 0, stream>>>((const half8*)PWp, XWp, c0, segS, segL, meta,
                                         (u64*)(W + offH), (int*)(W + offFL), out);
}

// Round 7
// 1798.555 us; speedup vs baseline: 3.7571x; 1.1599x over previous
//
#include <hip/hip_runtime.h>

typedef _Float16 half8 __attribute__((ext_vector_type(8)));
typedef float floatx4 __attribute__((ext_vector_type(4)));
typedef unsigned int u32x4 __attribute__((ext_vector_type(4)));
typedef unsigned long long u64;
typedef unsigned int u32;
typedef unsigned short u16;

#define T_LEN 16384
#define DM 512
#define NC 2048      // 4*DM
#define NG 16        // groups
#define NR 16        // segment rows (batch) per group
#define WPG 16       // workgroups per group
#define WVG 32       // compute waves per group (= flags per group)

struct Meta { int S; int use_h0; int steps_g[NG]; };

union FragU { u64 q[2]; u32x4 r; half8 v; };

__device__ __forceinline__ float sigf(float x) { return 1.0f / (1.0f + __expf(-x)); }
__device__ __forceinline__ float tanh_f(float x) { return 1.0f - 2.0f / (__expf(2.0f * x) + 1.0f); }

// ---------------- zero workspace region ----------------
__global__ void zero_kernel(u32* __restrict__ p, size_t nwords) {
    size_t i = (size_t)blockIdx.x * blockDim.x + threadIdx.x;
    size_t stride = (size_t)gridDim.x * blockDim.x;
    for (; i < nwords; i += stride) p[i] = 0u;
}

// ---------------- f32 -> f16 pack (row-major) ----------------
__global__ void pack_f16_kernel(const float* __restrict__ src, _Float16* __restrict__ dst, int n8) {
    int i = blockIdx.x * blockDim.x + threadIdx.x;
    if (i >= n8) return;
    const floatx4* s = (const floatx4*)src + (size_t)i * 2;
    floatx4 a = s[0], b = s[1];
    half8 o;
    o[0] = (_Float16)a[0]; o[1] = (_Float16)a[1]; o[2] = (_Float16)a[2]; o[3] = (_Float16)a[3];
    o[4] = (_Float16)b[0]; o[5] = (_Float16)b[1]; o[6] = (_Float16)b[2]; o[7] = (_Float16)b[3];
    ((half8*)dst)[i] = o;
}

// ---------------- weight pack to MFMA B-fragment order ----------------
__global__ __launch_bounds__(256) void pack_w_kernel(const float* __restrict__ src, half8* __restrict__ dst) {
    int wid = blockIdx.x * 4 + (threadIdx.x >> 6);  // 2048 = 128 tiles * 16 kt
    int l = threadIdx.x & 63;
    int tt = wid >> 4, kt = wid & 15;
    int q = tt & 3, cch = tt >> 2;
    int col = q * 512 + cch * 16 + (l & 15);
    int h = l >> 4;
    half8 o;
#pragma unroll
    for (int jj = 0; jj < 8; jj++) o[jj] = (_Float16)src[(size_t)(kt * 32 + h * 8 + jj) * NC + col];
    dst[(tt * 16 + kt) * 64 + l] = o;
}

// ---------------- prep: term dtype detect, segment extraction, chains ----------------
__global__ void prep_kernel(const void* __restrict__ termraw, const float* __restrict__ h0,
                            int* __restrict__ seg_start, int* __restrict__ seg_len,
                            Meta* __restrict__ meta, _Float16* __restrict__ Hbuf) {
    __shared__ int cnts[256], offs[256];
    __shared__ int nzm, oddnz, totS;
    __shared__ int chain[256];
    int tid = threadIdx.x;
    if (tid == 0) { nzm = 0; oddnz = 0; }
    __syncthreads();
    const unsigned char* tb = (const unsigned char*)termraw;
    const int* ti = (const int*)termraw;
    int lm = 0;
    for (int i = tid; i < T_LEN; i += 256) {
        if (tb[i]) {
            int p = i & 3;
            if (p == 1 || p == 2) lm |= 1;
            else if (p == 3) lm |= 2;
            else lm |= 4;
        }
    }
    if (lm) atomicOr(&nzm, lm);
    __syncthreads();
    int mm = nzm;
    int bytemode = (mm & 1) ? 1 : 0;
    int floatmode = (!bytemode && (mm & 2)) ? 1 : 0;
    int lo = 0;
    if (!bytemode && !floatmode) {
        for (int k2 = 2 * tid + 1; k2 < T_LEN; k2 += 512) if (ti[k2]) lo = 1;
    }
    if (lo) atomicOr(&oddnz, 1);
    __syncthreads();
    int i64mode = (!bytemode && !floatmode && oddnz == 0 && (mm & 4)) ? 1 : 0;
    const float* tf = (const float*)termraw;

    auto termAt = [&](int t) -> int {
        if (bytemode) return tb[t] != 0;
        if (floatmode) return tf[t] != 0.0f;
        if (i64mode) return (ti[2 * t] != 0) || (ti[2 * t + 1] != 0);
        return ti[t] != 0;
    };

    int base = tid * 64;
    int cnt = 0;
    for (int k = 0; k < 64; k++) {
        int t = base + k;
        if (t == 0 || termAt(t)) cnt++;
    }
    cnts[tid] = cnt;
    __syncthreads();
    if (tid == 0) {
        int a = 0;
        for (int i = 0; i < 256; i++) { offs[i] = a; a += cnts[i]; }
        totS = a;
        meta->S = a;
    }
    __syncthreads();
    int S = totS;
    {
        int o = offs[tid];
        for (int k = 0; k < 64; k++) {
            int t = base + k;
            if (t == 0 || termAt(t)) seg_start[o++] = t;
        }
    }
    __syncthreads();
    for (int i = tid; i < S; i += 256)
        seg_len[i] = ((i + 1 < S) ? seg_start[i + 1] : T_LEN) - seg_start[i];
    __syncthreads();
    {
        int g = tid >> 4, r = tid & 15;
        int tot = 0;
        for (int i = g + 16 * r; i < S; i += 256) tot += seg_len[i];
        chain[tid] = tot;
    }
    __syncthreads();
    if (tid < NG) {
        int mx = 0;
        for (int r = 0; r < 16; r++) mx = max(mx, chain[tid * 16 + r]);
        meta->steps_g[tid] = mx;
    }
    int u = termAt(0);
    if (tid == 0) meta->use_h0 = !u;
    if (!u) {
        // h0 seed into group0/parity0/row0, coalesced layout Hb[kt][hh][m=0][j]
        for (int d2 = tid; d2 < DM; d2 += 256)
            Hbuf[(d2 >> 3) * 128 + (d2 & 7)] = (_Float16)h0[d2];
    }
}

// ---------------- XW = inputs @ Wx + b (fp16 MFMA, packed-col order, fp16 out) ----------------
__global__ __launch_bounds__(256) void xw_gemm_kernel(const half8* __restrict__ A, const half8* __restrict__ B,
                                                      const float* __restrict__ bias, _Float16* __restrict__ XW) {
    int bx = blockIdx.x, by = blockIdx.y;
    int w = threadIdx.x >> 6, l = threadIdx.x & 63;
    int mbase = bx * 64 + w * 16;
    int h = l >> 4, n = l & 15;
    floatx4 acc[8] = {};
    int arow = mbase + n;
#pragma unroll
    for (int kt = 0; kt < 16; kt++) {
        half8 a = A[(size_t)arow * 64 + kt * 4 + h];
#pragma unroll
        for (int nt = 0; nt < 8; nt++)
            acc[nt] = __builtin_amdgcn_mfma_f32_16x16x32_f16(a, B[((by * 8 + nt) * 16 + kt) * 64 + l], acc[nt], 0, 0, 0);
    }
#pragma unroll
    for (int nt = 0; nt < 8; nt++) {
        int tt = by * 8 + nt, q = tt & 3, cch = tt >> 2;
        float bv = bias[q * 512 + cch * 16 + n];
#pragma unroll
        for (int r = 0; r < 4; r++) {
            int row = mbase + h * 4 + r;
            XW[(size_t)row * NC + tt * 16 + n] = (_Float16)(acc[nt][r] + bv);
        }
    }
}

// ---------------- per-thread segment tracker ----------------
struct Trk { int seg, t0, s0, end, active; };

__device__ __forceinline__ void trk_init(Trk& k, int row, int g, int S,
                                         const int* __restrict__ ss, const int* __restrict__ sl) {
    int seg = g + 16 * row;
    k.seg = seg;
    if (seg < S) { k.t0 = ss[seg]; k.s0 = 0; k.end = sl[seg]; k.active = 1; }
    else { k.t0 = 0; k.s0 = 0; k.end = 0x7fffffff; k.active = 0; }
}

__device__ __forceinline__ int trk_step(Trk& k, int s, int S,
                                        const int* __restrict__ ss, const int* __restrict__ sl, int& t_out) {
    int z = !k.active;
    if (s > 0 && k.active && s == k.end) {
        int seg = k.seg + 256;
        if (seg < S) { k.seg = seg; k.t0 = ss[seg]; k.s0 = s; k.end = s + sl[seg]; z = 1; }
        else { k.active = 0; z = 1; }
    }
    t_out = k.active ? (k.t0 + (s - k.s0)) : 0;
    return z;
}

// ---------------- recurrent scan v7: wave-specialized IO ----------------
// 3 waves/WG: waves 0,1 compute (R6 protocol; VMEM queue = MALL-only ops),
// wave 2 = IO: pre-stages XW(s+2) into LDS, drains out-stores from LDS stage.
// Rationale: vmcnt retires IN ORDER (m135) -> any HBM-latency op issued by a
// compute wave delays its subsequent flag-poll loads. IO wave absorbs them.
__global__ __launch_bounds__(192, 1) void scan_kernel(
    const half8* __restrict__ PW, const _Float16* __restrict__ XW,
    const float* __restrict__ c0,
    const int* __restrict__ seg_start, const int* __restrict__ seg_len,
    const Meta* __restrict__ meta,
    u64* __restrict__ Hbuf, int* __restrict__ flags,
    float* __restrict__ out) {
    const int b = blockIdx.x;
    const int g = (b & 7) * 2 + (b >> 7);   // XCD-local groups (perf hint only)
    const int jj = (b >> 3) & 15;
    const int tid = threadIdx.x;
    const int w = tid >> 6, l = tid & 63;
    const int S = meta->S;
    const int steps = meta->steps_g[g];
    if (steps <= 0) return;
    const int use_h0 = meta->use_h0;

    __shared__ __align__(16) u16 hstage[2][NR][16];
    __shared__ __align__(16) _Float16 xwstage[2][NR][128];   // [buf][row][WG's 128 packed cols]
    __shared__ __align__(16) float outstage[2][2][NR][32];   // [buf][h|c][row][WG's 32 dims]
    __shared__ int ioflag[2];   // step id staged in xwstage[b] (-1 = none)
    __shared__ int outcnt[2];   // 0=free, 1=one wave done, 2=ready for IO

    if (tid == 0) { ioflag[0] = -1; ioflag[1] = -1; outcnt[0] = 0; outcnt[1] = 0; }
    __syncthreads();

    float* outH = out;
    float* outC = out + (size_t)T_LEN * DM;
    float* outH2 = out + 2 * (size_t)T_LEN * DM;

    if (w < 2) {
        // ================= COMPUTE WAVE =================
        const int c = jj * 2 + w;               // dim chunk 0..31 (16 dims each)
        const int n = l & 15, h = l >> 4;
        const int d = c * 16 + n;

        half8 bf[4][16];
#pragma unroll
        for (int q = 0; q < 4; q++)
#pragma unroll
            for (int kt = 0; kt < 16; kt++) {
                bf[q][kt] = PW[((c * 4 + q) * 16 + kt) * 64 + l];
                asm volatile("" : "+v"(bf[q][kt]));
            }

        Trk trkM; trk_init(trkM, n, g, S, seg_start, seg_len);
        Trk trk[4];
#pragma unroll
        for (int r = 0; r < 4; r++) trk_init(trk[r], h * 4 + r, g, S, seg_start, seg_len);

        float cc[4];
#pragma unroll
        for (int r = 0; r < 4; r++) {
            int row = h * 4 + r;
            cc[r] = (g == 0 && row == 0 && use_h0) ? c0[d] : 0.0f;
        }

        FragU zu; zu.q[0] = 0; zu.q[1] = 0;
        const half8 zfrag = zu.v;

        int* fl = flags + g * WVG;
        const int wfid = jj * 2 + w;
        const int pollidx = l & 31;

        // producer store coords (coalesced layout)
        const int b2 = l >> 5, m2 = (l >> 1) & 15, half = l & 1;
        const int ktc = c >> 1, hhp = (c & 1) * 2 + b2;
        const int ldsIdx = m2 * 4 + b2 * 2 + half;
        const size_t hwIdx = (size_t)(ktc * 4 + hhp) * 32 + m2 * 2 + half;

        for (int s = 0; s < steps; ++s) {
            // ---- trackers for step s (registers; rare L2 loads on transitions) ----
            int tdump;
            const int zM = trk_step(trkM, s, S, seg_start, seg_len, tdump);
            int zz[4];
#pragma unroll
            for (int r = 0; r < 4; r++)
                zz[r] = trk_step(trk[r], s, S, seg_start, seg_len, tdump);

            // ---- XW(s) from LDS stage (lgkm only; pre-staged by IO wave) ----
            while (__hip_atomic_load(&ioflag[s & 1], __ATOMIC_RELAXED, __HIP_MEMORY_SCOPE_WORKGROUP) < s)
                __builtin_amdgcn_s_sleep(1);
            asm volatile("" ::: "memory");
            float xwv[4][4];
#pragma unroll
            for (int q = 0; q < 4; q++)
#pragma unroll
                for (int r = 0; r < 4; r++)
                    xwv[q][r] = (float)xwstage[s & 1][h * 4 + r][w * 64 + q * 16 + n];

            // ---- wait peers' step-(s-1) H publish (clean MALL-only queue) ----
            if (s > 0) {
                while (true) {
                    int v = __hip_atomic_load(&fl[pollidx], __ATOMIC_RELAXED, __HIP_MEMORY_SCOPE_AGENT);
                    if (__all(v >= s)) break;
                    __builtin_amdgcn_s_sleep(1);
                }
                asm volatile("" ::: "memory");
            }

            const int rp = s & 1;
            u64* Hr = Hbuf + (size_t)(g * 2 + rp) * (NR * DM / 4);
            u64* Hw = Hbuf + (size_t)(g * 2 + (rp ^ 1)) * (NR * DM / 4);

            // ---- A-fragment burst: 16 x dwordx4 sc1 ----
            const int m = n;
            u32x4 raw[16];
#pragma unroll
            for (int kt = 0; kt < 16; kt++) {
                const void* ap = (const char*)Hr + (((size_t)kt * 64 + h * 16 + m) << 4);
                asm volatile("global_load_dwordx4 %0, %1, off sc1" : "=v"(raw[kt]) : "v"(ap) : "memory");
            }
            asm volatile("s_waitcnt vmcnt(0)" ::: "memory");
            __builtin_amdgcn_sched_barrier(0);
            half8 afr[16];
#pragma unroll
            for (int kt = 0; kt < 16; kt++) {
                FragU u; u.r = raw[kt];
                afr[kt] = zM ? zfrag : u.v;
            }

            floatx4 acc[4] = {};
#pragma unroll
            for (int kt = 0; kt < 16; kt++) {
#pragma unroll
                for (int q = 0; q < 4; q++)
                    acc[q] = __builtin_amdgcn_mfma_f32_16x16x32_f16(afr[kt], bf[q][kt], acc[q], 0, 0, 0);
            }

            float hnv[4], cnv[4];
#pragma unroll
            for (int r = 0; r < 4; r++) {
                float zi = acc[0][r] + xwv[0][r];
                float zf = acc[1][r] + xwv[1][r];
                float zg = acc[2][r] + xwv[2][r];
                float zo = acc[3][r] + xwv[3][r];
                float cprev = zz[r] ? 0.0f : cc[r];
                float cn = sigf(zf) * cprev + sigf(zi) * tanh_f(zg);
                float hn = sigf(zo) * tanh_f(cn);
                cc[r] = cn; hnv[r] = hn; cnv[r] = cn;
                hstage[w][h * 4 + r][n] = __builtin_bit_cast(u16, (_Float16)hn);
            }

            // wave-local regroup via LDS; order u16-writes -> u64-read (R3 lesson)
            asm volatile("s_waitcnt lgkmcnt(0)" ::: "memory");
            __builtin_amdgcn_sched_barrier(0);
            u64 pk = ((const u64*)&hstage[w][0][0])[ldsIdx];
            __hip_atomic_store(&Hw[hwIdx], pk, __ATOMIC_RELAXED, __HIP_MEMORY_SCOPE_AGENT);

            // drain this wave's H store (only op in queue), publish wave flag
            asm volatile("s_waitcnt vmcnt(0)" ::: "memory");
            if (l == 0)
                __hip_atomic_store(&fl[wfid], s + 1, __ATOMIC_RELAXED, __HIP_MEMORY_SCOPE_AGENT);

            // ---- hand outputs to IO wave via LDS (lgkm traffic only) ----
            while (__hip_atomic_load(&outcnt[s & 1], __ATOMIC_RELAXED, __HIP_MEMORY_SCOPE_WORKGROUP) == 2)
                __builtin_amdgcn_s_sleep(1);
            asm volatile("" ::: "memory");
#pragma unroll
            for (int r = 0; r < 4; r++) {
                outstage[s & 1][0][h * 4 + r][w * 16 + n] = hnv[r];
                outstage[s & 1][1][h * 4 + r][w * 16 + n] = cnv[r];
            }
            asm volatile("s_waitcnt lgkmcnt(0)" ::: "memory");
            if (l == 0)
                __hip_atomic_fetch_add(&outcnt[s & 1], 1, __ATOMIC_RELAXED, __HIP_MEMORY_SCOPE_WORKGROUP);
        }
    } else {
        // ================= IO WAVE =================
        const int rX = l >> 4;        // staging rows rX+4i, lane part (l&15)
        const int rO = l >> 3;        // out rows rO, rO+8, lane part (l&7)
        Trk trkX[4];
#pragma unroll
        for (int i = 0; i < 4; i++) trk_init(trkX[i], rX + 4 * i, g, S, seg_start, seg_len);
        Trk trkO[2];
        trk_init(trkO[0], rO, g, S, seg_start, seg_len);
        trk_init(trkO[1], rO + 8, g, S, seg_start, seg_len);

        auto stageXW = [&](int step, int buf) {
            int tX[4], td;
#pragma unroll
            for (int i = 0; i < 4; i++) (void)trk_step(trkX[i], step, S, seg_start, seg_len, tX[i]);
            u32x4 xr[4];
#pragma unroll
            for (int i = 0; i < 4; i++)
                xr[i] = *(const u32x4*)((const char*)XW + ((size_t)tX[i] * NC + jj * 128 + (l & 15) * 8) * 2);
            (void)td;
#pragma unroll
            for (int i = 0; i < 4; i++)
                *(u32x4*)&xwstage[buf][rX + 4 * i][(l & 15) * 8] = xr[i];
            asm volatile("s_waitcnt lgkmcnt(0)" ::: "memory");
            if (l == 0)
                __hip_atomic_store(&ioflag[buf], step, __ATOMIC_RELAXED, __HIP_MEMORY_SCOPE_WORKGROUP);
        };

        // prologue: stage XW(0), XW(1)
        stageXW(0, 0);
        stageXW(1, 1);

        for (int s = 0; s < steps; ++s) {
            // trackers for out rows at step s
            int tO[2], aO[2];
#pragma unroll
            for (int j2 = 0; j2 < 2; j2++) {
                (void)trk_step(trkO[j2], s, S, seg_start, seg_len, tO[j2]);
                aO[j2] = trkO[j2].active;
            }
            // wait both compute waves' outstage for step s
            while (__hip_atomic_load(&outcnt[s & 1], __ATOMIC_RELAXED, __HIP_MEMORY_SCOPE_WORKGROUP) < 2)
                __builtin_amdgcn_s_sleep(1);
            asm volatile("" ::: "memory");
            floatx4 hv[2], cv[2];
#pragma unroll
            for (int j2 = 0; j2 < 2; j2++) {
                hv[j2] = *(floatx4*)&outstage[s & 1][0][rO + 8 * j2][(l & 7) * 4];
                cv[j2] = *(floatx4*)&outstage[s & 1][1][rO + 8 * j2][(l & 7) * 4];
            }
            asm volatile("s_waitcnt lgkmcnt(0)" ::: "memory");
            __hip_atomic_store(&outcnt[s & 1], 0, __ATOMIC_RELAXED, __HIP_MEMORY_SCOPE_WORKGROUP);
#pragma unroll
            for (int j2 = 0; j2 < 2; j2++) {
                if (aO[j2]) {
                    size_t base = (size_t)tO[j2] * DM + jj * 32 + (l & 7) * 4;
                    *(floatx4*)&outH[base] = hv[j2];
                    *(floatx4*)&outC[base] = cv[j2];
                    *(floatx4*)&outH2[base] = hv[j2];
                }
            }
            // re-stage this buffer with XW(s+2) (buffer freed: step-s compute done)
            stageXW(s + 2, s & 1);
        }
    }
}

extern "C" void kernel_launch(void* const* d_in, const int* in_sizes, int n_in,
                              void* d_out, int out_size, void* d_ws, size_t ws_size,
                              hipStream_t stream) {
    const float* inputs = (const float*)d_in[0];
    const void* terms = d_in[1];
    const float* c0 = (const float*)d_in[2];
    const float* h0 = (const float*)d_in[3];
    const float* Wx = (const float*)d_in[4];
    const float* Wh = (const float*)d_in[5];
    const float* bias = (const float*)d_in[6];
    float* out = (float*)d_out;

    size_t off = 0;
    auto take = [&](size_t bts) { size_t cur = off; off = (off + bts + 255) & ~(size_t)255; return cur; };
    size_t offXW = take((size_t)T_LEN * NC * 2);       // fp16 XW
    size_t offAin = take((size_t)T_LEN * DM * 2);
    size_t offPX = take((size_t)DM * NC * 2);
    size_t offPW = take((size_t)DM * NC * 2);
    size_t offSS = take((size_t)(T_LEN + 2) * 4);
    size_t offSL = take((size_t)(T_LEN + 2) * 4);
    size_t offH = take(2ull * NG * NR * DM * 2);
    size_t offFL = take((size_t)NG * WVG * 4);
    size_t offME = take(256);
    size_t total = off;
    (void)ws_size;

    char* W = (char*)d_ws;
    _Float16* Ain = (_Float16*)(W + offAin);
    half8* PX = (half8*)(W + offPX);
    half8* PWp = (half8*)(W + offPW);
    int* segS = (int*)(W + offSS);
    int* segL = (int*)(W + offSL);
    Meta* meta = (Meta*)(W + offME);
    _Float16* XWp = (_Float16*)(W + offXW);

    size_t zwords = (total - offH) / 4;  // Hbuf + flags + meta contiguous
    zero_kernel<<<256, 256, 0, stream>>>((u32*)(W + offH), zwords);
    pack_f16_kernel<<<(T_LEN * DM / 8 + 255) / 256, 256, 0, stream>>>(inputs, Ain, T_LEN * DM / 8);
    pack_w_kernel<<<512, 256, 0, stream>>>(Wx, PX);
    pack_w_kernel<<<512, 256, 0, stream>>>(Wh, PWp);
    prep_kernel<<<1, 256, 0, stream>>>(terms, h0, segS, segL, meta, (_Float16*)(W + offH));

    dim3 gg(T_LEN / 64, NC / 128);
    xw_gemm_kernel<<<gg, 256, 0, stream>>>((const half8*)Ain, (const half8*)PX, bias, XWp);
    scan_kernel<<<256, 192, 0, stream>>>((const half8*)PWp, XWp, c0, segS, segL, meta,
                                         (u64*)(W + offH), (int*)(W + offFL), out);
}